// Round 13
// baseline (505.955 us; speedup 1.0000x reference)
//
#include <hip/hip_runtime.h>
#include <cstddef>
#include <cstdint>

#define BN    32768   // B*N
#define NG    4096    // nodes per graph
#define KNN   24
#define KPW   14      // per-lane partial top over its 1/8 candidate subset
#define KM    32      // merged candidate pool for exact refine
#define CHK   128     // candidates per chunk
#define NBQ   64      // queries per knn block
#define STKD  16      // pending-stack depth per lane
#define TRIG  13      // flush trigger: pcnt<=12 pre-tile, +4 writes at slots<=15

typedef float f32x4_t __attribute__((ext_vector_type(4)));
typedef short s16x8_t __attribute__((ext_vector_type(8)));

__device__ __forceinline__ float elu_f(float x) {
    return x > 0.f ? x : expm1f(x);
}

__device__ __forceinline__ unsigned short f2bf(float f) {
    unsigned u = __float_as_uint(f);
    unsigned r = (u + 0x7FFFu + ((u >> 16) & 1u)) >> 16;   // RNE
    return (unsigned short)r;
}

// pack one node's 32 features: bf16 linear, bf16 MFMA-A-tiled, bf16-consistent d2
__device__ __forceinline__ void pack_node(int n, const float* hv,
    unsigned short* __restrict__ hbf, unsigned short* __restrict__ til,
    float* __restrict__ d2b)
{
    __align__(16) unsigned short us[32];
    float s = 0.f;
#pragma unroll
    for (int k = 0; k < 32; ++k) {
        us[k] = f2bf(hv[k]);
        float v = __uint_as_float(((unsigned)us[k]) << 16);
        s = fmaf(v, v, s);
    }
    d2b[n] = s;
    const uint4* up = reinterpret_cast<const uint4*>(us);
    uint4* lp = reinterpret_cast<uint4*>(hbf + (size_t)n * 32);
#pragma unroll
    for (int j = 0; j < 4; ++j) lp[j] = up[j];
    const int g = n >> 12, ln = n & 4095, tile = ln >> 4, c = ln & 15;
    unsigned short* tb = til + (size_t)g * 131072 + tile * 512 + c * 8;
#pragma unroll
    for (int kg = 0; kg < 4; ++kg)
        *reinterpret_cast<uint4*>(tb + kg * 128) = up[kg];
}

// ---------------- encoder: x[BN,4] -> h[BN,32] (+bf16 pack, d2, d2b) ----------------
// 256 blocks x 128 threads: one block per CU (all 256 CUs active)
__global__ __launch_bounds__(128) void k_encoder(
    const float* __restrict__ x,
    const float* __restrict__ w1, const float* __restrict__ b1,
    const float* __restrict__ w2, const float* __restrict__ b2,
    float* __restrict__ hOut, float* __restrict__ d2Out,
    unsigned short* __restrict__ hbf, unsigned short* __restrict__ til,
    float* __restrict__ d2b)
{
    __shared__ float sw1[4 * 32];
    __shared__ float sb1[32];
    __shared__ float sw2[32 * 32];
    __shared__ float sb2[32];
    int tid = threadIdx.x;
    sw1[tid] = w1[tid];                     // 128 threads, 128 entries
    if (tid < 32) sb1[tid] = b1[tid];
    for (int i = tid; i < 1024; i += 128) sw2[i] = w2[i];
    if (tid >= 32 && tid < 64) sb2[tid - 32] = b2[tid - 32];
    __syncthreads();

    int node = blockIdx.x * 128 + tid;
    float4 xv = reinterpret_cast<const float4*>(x)[node];

    float h1[32];
#pragma unroll
    for (int o = 0; o < 32; ++o) {
        float s = sb1[o];
        s = fmaf(xv.x, sw1[o], s);
        s = fmaf(xv.y, sw1[32 + o], s);
        s = fmaf(xv.z, sw1[64 + o], s);
        s = fmaf(xv.w, sw1[96 + o], s);
        h1[o] = elu_f(s);
    }
    float h2[32];
    float d2 = 0.f;
#pragma unroll
    for (int o = 0; o < 32; ++o) {
        float s = sb2[o];
#pragma unroll
        for (int f = 0; f < 32; ++f) s = fmaf(h1[f], sw2[f * 32 + o], s);
        float v = elu_f(s);
        h2[o] = v;
        d2 = fmaf(v, v, d2);
    }
    float4* hp = reinterpret_cast<float4*>(hOut) + (size_t)node * 8;
#pragma unroll
    for (int j = 0; j < 8; ++j)
        hp[j] = make_float4(h2[4 * j], h2[4 * j + 1], h2[4 * j + 2], h2[4 * j + 3]);
    d2Out[node] = d2;
    pack_node(node, h2, hbf, til, d2b);
}

// sorted-ascending chain insert into top[KPW]
#define CHAIN14(nk_) do { \
    unsigned nk = (nk_); \
    _Pragma("unroll") \
    for (int jj = 0; jj < KPW; ++jj) { \
        unsigned tj = top[jj]; \
        unsigned lo = nk < tj ? nk : tj; \
        unsigned hi = nk < tj ? tj : nk; \
        top[jj] = lo; nk = hi; \
    } \
} while (0)

// ------------- MFMA kNN scan + parallel rank-to-pool -------------
// 512 blocks x 512 threads; block = 64 queries, 8 waves = 4 query tiles x 2
// cand-tile parities. LDS = 32KB (stacks only) -> 4 blocks/CU x 8 waves =
// 32 waves/CU: k_scan is VALU-issue-bound (R12: 73% VALUBusy at 3 blocks/CU),
// so doubling resident waves raises issue utilization toward the ~83us floor.
// Candidate d2 is read per-chunk from global (d2b is 16KB/graph, L2-resident,
// 16-lane broadcast f32x4 -> 64B/group) instead of a 16KB LDS stage — the
// ONLY change vs the 113.6us R11/R12 kernel (R3/R5 occupancy attempts failed
// from launch-bounds spills, R6 from halved per-block work; this holds both).
// Scan is fully barrier-free; per-lane sorted top-14 via 16-deep stacks;
// accept path branchless/exec-free; rank-to-pool as R11 (q-major stride-15).
__global__ __launch_bounds__(512, 4) void k_scan(
    const unsigned short* __restrict__ til,
    const unsigned short* __restrict__ hbf,
    const float* __restrict__ d2b,
    unsigned short* __restrict__ mgs)
{
    __shared__ __align__(16) unsigned char smem[32768];
    constexpr int STK = 0;        // 8 waves x 4096B pending stacks (16 deep)
    constexpr int LST = 0;        // lists reuse stacks after drain: 30720B

    const int tid = threadIdx.x;
    const int lane = tid & 63;
    const int wid = __builtin_amdgcn_readfirstlane(tid >> 6);
    const int qt = wid >> 1;
    const int par = wid & 1;
    const int bid = blockIdx.x;
    const int g = bid >> 6;
    const int gbase = g << 12;
    const int blockq = (bid & 63) * NBQ;
    const int qnode = gbase + blockq + qt * 16 + (lane & 15);
    const int rg = (lane >> 4) * 4;   // candidate row group base within tile

    // B fragment: query (lane&15) of this wave's tile, k-slice (lane>>4)*8..+8
    s16x8_t bfrag = *reinterpret_cast<const s16x8_t*>(
        hbf + (size_t)qnode * 32 + (lane >> 4) * 8);
    const float qd2 = d2b[qnode];
    const float nqd2h = -0.5f * qd2;

    unsigned top[KPW];
#pragma unroll
    for (int j = 0; j < KPW; ++j) top[j] = 0xFFFFFFFFu;
    unsigned thresh = 0xFFFFFFFFu;
    int pcnt = 0;

    // this wave's A-fragment stream base: tiles {par, par+2, par+4, par+6}
    const char* gtw = (const char*)til + (size_t)g * 262144
                    + (size_t)par * 1024 + (size_t)lane * 16;
    const float* d2g = d2b + gbase;   // whole-graph cand d2 (L2-resident)
    // per-lane element pointer into this wave's stack: slot j at stkl[j*64]
    unsigned* stkl = reinterpret_cast<unsigned*>(smem + STK + wid * 4096) + lane;

    // prologue: prefetch chunk 0 A-fragments into registers
    s16x8_t af[4];
#pragma unroll
    for (int i = 0; i < 4; ++i)
        af[i] = *reinterpret_cast<const s16x8_t*>(gtw + i * 2048);

    for (int c = 0; c < 32; ++c) {
        // candidate d2 for this chunk's 4 tiles (global/L2, 16-lane broadcast)
        f32x4_t cv[4];
#pragma unroll
        for (int i = 0; i < 4; ++i)
            cv[i] = *reinterpret_cast<const f32x4_t*>(
                d2g + c * 128 + (i * 2 + par) * 16 + rg);
        s16x8_t an[4];
        if (c < 31) {
#pragma unroll
            for (int i = 0; i < 4; ++i)
                an[i] = *reinterpret_cast<const s16x8_t*>(
                    gtw + (size_t)(c + 1) * 8192 + i * 2048);
        } else {
#pragma unroll
            for (int i = 0; i < 4; ++i) an[i] = af[i];
        }
#pragma unroll
        for (int i = 0; i < 4; ++i) {
            const int t = i * 2 + par;
            f32x4_t acc;
#pragma unroll
            for (int r = 0; r < 4; ++r) acc[r] = fmaf(-0.5f, cv[i][r], nqd2h);
            acc = __builtin_amdgcn_mfma_f32_16x16x32_bf16(af[i], bfrag, acc, 0, 0, 0);
            const int cid0 = c * CHK + t * 16 + rg;
#pragma unroll
            for (int r = 0; r < 4; ++r) {
                // acc = -(d/2) <= 0; unsigned-ascending bit pattern == ascending d.
                unsigned key = (__float_as_uint(acc[r]) & 0xFFFFF000u)
                             | (unsigned)(cid0 + r);
                // branchless, exec-free accept
                stkl[pcnt * 64] = key;
                pcnt += (key < thresh) ? 1 : 0;
            }
            if (__any(pcnt >= TRIG)) {
#pragma unroll 1
                for (int j = 0; j < STKD; ++j) {
                    if (!__any(pcnt > j)) break;
                    unsigned kk = stkl[j * 64];                   // uncond read
                    unsigned k = (j < pcnt) ? kk : 0xFFFFFFFFu;   // select
                    CHAIN14(k);
                }
                pcnt = 0;
                thresh = top[KPW - 1];
            }
        }
#pragma unroll
        for (int i = 0; i < 4; ++i) af[i] = an[i];
    }
    // final drain
#pragma unroll 1
    for (int j = 0; j < STKD; ++j) {
        if (!__any(pcnt > j)) break;
        unsigned kk = stkl[j * 64];
        unsigned k = (j < pcnt) ? kk : 0xFFFFFFFFu;
        CHAIN14(k);
    }
    __syncthreads();   // all drains done before list region overwrites stacks

    // dump sorted lists: q-major, stride-15 (list (q,li) at lst + q*120 + li*15)
    unsigned* lst = reinterpret_cast<unsigned*>(smem + LST);
    const int q_d  = qt * 16 + (lane & 15);   // this thread's query
    const int li_d = par * 4 + (lane >> 4);   // this thread's list id
    {
        unsigned* myrow = lst + q_d * 120 + li_d * 15;
#pragma unroll
        for (int j = 0; j < KPW; ++j) myrow[j] = top[j];
    }
    __syncthreads();

    // parallel rank-to-pool (identity mapping: my list is top[] in regs).
    // rank(top[j]) = j + sum over 7 peers of #{peer key < top[j]}.
    {
        int rk[KPW];
#pragma unroll
        for (int j = 0; j < KPW; ++j) rk[j] = j;
        const unsigned* base = lst + q_d * 120;
#pragma unroll 1
        for (int u = 1; u < 8; ++u) {
            const unsigned* pl = base + ((li_d + u) & 7) * 15;
            unsigned pk[KPW];
#pragma unroll
            for (int k = 0; k < KPW; ++k) pk[k] = pl[k];   // independent reads
#pragma unroll
            for (int k = 0; k < KPW; ++k) {
#pragma unroll
                for (int j = 0; j < KPW; ++j)
                    rk[j] += (pk[k] < top[j]) ? 1 : 0;
            }
        }
        unsigned short* mrow = mgs + (size_t)(gbase + blockq + q_d) * 32;
#pragma unroll
        for (int j = 0; j < KPW; ++j)
            if (rk[j] < KM) mrow[rk[j]] = (unsigned short)(top[j] & 0xFFFu);
    }
}

// ------------- refine: exact top-24 from the KM pool + A/Bv precompute -------------
// 2048 blocks x 128 threads, 16 queries/block (8 lanes/query), one barrier.
// P2 is COOPERATIVE: per candidate, the query's 8 lanes load the row
// coalesced (8 x 16B = one 128B segment) and butterfly-reduce partial dots
// (__shfl_xor width=8) so every lane holds all 32 exact distances in
// statically-indexed registers. Rank-select is lane-local. A/B reads the
// full q row from a 2KB LDS stage (broadcast reads, conflict-free).
__global__ __launch_bounds__(128) void k_refine(
    const unsigned short* __restrict__ mgs,
    const float* __restrict__ hf,
    const float* __restrict__ d2x,
    const float* __restrict__ cw, const float* __restrict__ cb,
    int* __restrict__ idxOut,
    float* __restrict__ Abuf, float* __restrict__ Bbuf)
{
    __shared__ float sw[2048];
    __shared__ float sb[32];
    __shared__ __align__(16) float shq[16][32];   // block's 16 q rows

    const int tid = threadIdx.x;
    const int bid = blockIdx.x;
    const int g = bid >> 8;
    const int gbase = g << 12;
    const int blockq = (bid & 255) * 16;

    const int q  = tid >> 3;        // 0..15
    const int s0 = tid & 7;
    const int qn = gbase + blockq + q;

    // my 16B chunk of the q row (feeds P2 partial dots AND the LDS stage)
    const float4 qc = reinterpret_cast<const float4*>(hf)[(size_t)qn * 8 + s0];

    for (int i = tid; i < 2048; i += 128) sw[i] = cw[i];
    if (tid < 32) sb[tid] = cb[tid];
    *reinterpret_cast<float4*>(&shq[q][s0 * 4]) = qc;
    __syncthreads();   // the only barrier

    const float qd2e = d2x[qn];

    // P2: cooperative exact distances; all 32 land in per-lane registers
    float dall[32];
    float d_own[4];
    int cid_own[4];
#pragma unroll
    for (int i = 0; i < 4; ++i) { d_own[i] = 0.f; cid_own[i] = 0; }
#pragma unroll
    for (int s = 0; s < 32; ++s) {
        const int cid = (int)mgs[(size_t)qn * 32 + s];   // group-uniform load
        const int cn = gbase + cid;
        const float4 cc = reinterpret_cast<const float4*>(hf)[(size_t)cn * 8 + s0];
        float p = qc.x * cc.x;
        p = fmaf(qc.y, cc.y, p);
        p = fmaf(qc.z, cc.z, p);
        p = fmaf(qc.w, cc.w, p);
        p += __shfl_xor(p, 1, 8);
        p += __shfl_xor(p, 2, 8);
        p += __shfl_xor(p, 4, 8);   // all 8 lanes: full dot
        const float dv = fmaf(-2.f, p, qd2e + d2x[cn]);
        dall[s] = dv;
        // capture owned slots (s & 7 == s0) with static destination index
        const bool own = ((s & 7) == s0);
        d_own[s >> 3]   = own ? dv  : d_own[s >> 3];
        cid_own[s >> 3] = own ? cid : cid_own[s >> 3];
    }

    // P3: lane-local rank-select of owned cands (slots s0+8i); ranks unique
    {
        int* o = idxOut + (size_t)qn * KNN;
#pragma unroll
        for (int i = 0; i < 4; ++i) {
            const int mys = s0 + 8 * i;
            const float di = d_own[i];
            int rank = 0;
#pragma unroll
            for (int j = 0; j < 32; ++j)
                rank += (dall[j] < di || (dall[j] == di && j < mys)) ? 1 : 0;
            if (rank < KNN) o[rank] = cid_own[i];
        }
    }

    // A/B precompute: A = h@(W1-W2)+b, Bv = h@W2 (full q row from LDS stage)
    {
        const int o0 = s0 * 4;
        const float* hr = shq[q];
        float4 s1 = make_float4(0.f, 0.f, 0.f, 0.f);
        float4 s2 = make_float4(0.f, 0.f, 0.f, 0.f);
#pragma unroll
        for (int f = 0; f < 32; ++f) {
            float hv = hr[f];
            float4 wa = *reinterpret_cast<const float4*>(sw + f * 32 + o0);
            float4 wb = *reinterpret_cast<const float4*>(sw + (32 + f) * 32 + o0);
            s1.x = fmaf(hv, wa.x, s1.x); s1.y = fmaf(hv, wa.y, s1.y);
            s1.z = fmaf(hv, wa.z, s1.z); s1.w = fmaf(hv, wa.w, s1.w);
            s2.x = fmaf(hv, wb.x, s2.x); s2.y = fmaf(hv, wb.y, s2.y);
            s2.z = fmaf(hv, wb.z, s2.z); s2.w = fmaf(hv, wb.w, s2.w);
        }
        float4 bv = *reinterpret_cast<const float4*>(sb + o0);
        float4 av = make_float4(s1.x - s2.x + bv.x, s1.y - s2.y + bv.y,
                                s1.z - s2.z + bv.z, s1.w - s2.w + bv.w);
        *reinterpret_cast<float4*>(Abuf + (size_t)qn * 32 + o0) = av;
        *reinterpret_cast<float4*>(Bbuf + (size_t)qn * 32 + o0) = s2;
    }
}

// ------------- aggregate: h_out = elu(A + max_k Bv[nbr]); LAST: fused output MLP -------------
template <bool LAST>
__global__ __launch_bounds__(128) void k_aggregate(
    const float* __restrict__ A, const float* __restrict__ Bv,
    const int* __restrict__ idx,
    float* __restrict__ hOut, float* __restrict__ d2Out,
    unsigned short* __restrict__ hbf, unsigned short* __restrict__ til,
    float* __restrict__ d2b,
    const float* __restrict__ w1, const float* __restrict__ b1,
    const float* __restrict__ w2, const float* __restrict__ b2,
    const float* __restrict__ w3, const float* __restrict__ b3,
    float* __restrict__ out)
{
    __shared__ float sw1[1024];
    __shared__ float sb1[32];
    __shared__ float sw2[512];
    __shared__ float sb2[16];
    __shared__ float sw3[128];
    __shared__ float sb3[8];
    int tid = threadIdx.x;
    if (LAST) {
        for (int i = tid; i < 1024; i += 128) sw1[i] = w1[i];
        for (int i = tid; i < 512; i += 128) sw2[i] = w2[i];
        sw3[tid] = w3[tid];                      // 128 threads, 128 entries
        if (tid < 32) sb1[tid] = b1[tid];
        if (tid >= 32 && tid < 48) sb2[tid - 32] = b2[tid - 32];
        if (tid >= 48 && tid < 56) sb3[tid - 48] = b3[tid - 48];
        __syncthreads();
    }

    int node = blockIdx.x * 128 + tid;
    int g = node >> 12;
    const int* ip = idx + (size_t)node * KNN;

    float4 m[8];
#pragma unroll
    for (int j = 0; j < 8; ++j) m[j] = make_float4(-1e30f, -1e30f, -1e30f, -1e30f);

    for (int k = 0; k < KNN; ++k) {
        int cand = (g << 12) + ip[k];
        const float4* bp = reinterpret_cast<const float4*>(Bv) + (size_t)cand * 8;
#pragma unroll
        for (int j = 0; j < 8; ++j) {
            float4 b = bp[j];
            m[j].x = fmaxf(m[j].x, b.x);
            m[j].y = fmaxf(m[j].y, b.y);
            m[j].z = fmaxf(m[j].z, b.z);
            m[j].w = fmaxf(m[j].w, b.w);
        }
    }
    const float4* ap = reinterpret_cast<const float4*>(A) + (size_t)node * 8;
    float hv[32];
    float d2 = 0.f;
#pragma unroll
    for (int j = 0; j < 8; ++j) {
        float4 a = ap[j];
        float4 v;
        v.x = elu_f(a.x + m[j].x);
        v.y = elu_f(a.y + m[j].y);
        v.z = elu_f(a.z + m[j].z);
        v.w = elu_f(a.w + m[j].w);
        d2 = fmaf(v.x, v.x, d2);
        d2 = fmaf(v.y, v.y, d2);
        d2 = fmaf(v.z, v.z, d2);
        d2 = fmaf(v.w, v.w, d2);
        hv[4 * j] = v.x; hv[4 * j + 1] = v.y; hv[4 * j + 2] = v.z; hv[4 * j + 3] = v.w;
    }

    if (!LAST) {
        float4* hp = reinterpret_cast<float4*>(hOut) + (size_t)node * 8;
#pragma unroll
        for (int j = 0; j < 8; ++j)
            hp[j] = make_float4(hv[4 * j], hv[4 * j + 1], hv[4 * j + 2], hv[4 * j + 3]);
        d2Out[node] = d2;
        pack_node(node, hv, hbf, til, d2b);
    } else {
        float o1[32];
#pragma unroll
        for (int o = 0; o < 32; ++o) {
            float s = sb1[o];
#pragma unroll
            for (int f = 0; f < 32; ++f) s = fmaf(hv[f], sw1[f * 32 + o], s);
            o1[o] = elu_f(s);
        }
        float o2[16];
#pragma unroll
        for (int o = 0; o < 16; ++o) {
            float s = sb2[o];
#pragma unroll
            for (int f = 0; f < 32; ++f) s = fmaf(o1[f], sw2[f * 16 + o], s);
            o2[o] = elu_f(s);
        }
        float o3[8];
#pragma unroll
        for (int o = 0; o < 8; ++o) {
            float s = sb3[o];
#pragma unroll
            for (int f = 0; f < 16; ++f) s = fmaf(o2[f], sw3[f * 8 + o], s);
            o3[o] = s;
        }
        float4* op = reinterpret_cast<float4*>(out) + (size_t)node * 2;
        op[0] = make_float4(o3[0], o3[1], o3[2], o3[3]);
        op[1] = make_float4(o3[4], o3[5], o3[6], o3[7]);
        out[(size_t)BN * 8 + node] = (float)(node >> 12);
    }
}

extern "C" void kernel_launch(void* const* d_in, const int* in_sizes, int n_in,
                              void* d_out, int out_size, void* d_ws, size_t ws_size,
                              hipStream_t stream)
{
    (void)in_sizes; (void)n_in; (void)out_size; (void)ws_size;
    const float* x      = (const float*)d_in[0];
    const float* enc_w1 = (const float*)d_in[2];
    const float* enc_b1 = (const float*)d_in[3];
    const float* enc_w2 = (const float*)d_in[4];
    const float* enc_b2 = (const float*)d_in[5];
    const float* conv_w[3] = { (const float*)d_in[6], (const float*)d_in[8], (const float*)d_in[10] };
    const float* conv_b[3] = { (const float*)d_in[7], (const float*)d_in[9], (const float*)d_in[11] };
    const float* out_w1 = (const float*)d_in[12];
    const float* out_b1 = (const float*)d_in[13];
    const float* out_w2 = (const float*)d_in[14];
    const float* out_b2 = (const float*)d_in[15];
    const float* out_w3 = (const float*)d_in[16];
    const float* out_b3 = (const float*)d_in[17];

    char* ws = (char*)d_ws;
    float*          hA   = (float*)(ws + 0);                  // 4 MB
    float*          hB   = (float*)(ws + 4194304);            // 4 MB
    unsigned short* hbfA = (unsigned short*)(ws + 8388608);   // 2 MB
    unsigned short* hbfB = (unsigned short*)(ws + 10485760);  // 2 MB
    unsigned short* tilA = (unsigned short*)(ws + 12582912);  // 2 MB
    unsigned short* tilB = (unsigned short*)(ws + 14680064);  // 2 MB
    float*          d2A  = (float*)(ws + 16777216);           // 128 KB
    float*          d2B  = (float*)(ws + 16908288);           // 128 KB
    float*          d2bA = (float*)(ws + 17039360);           // 128 KB
    float*          d2bB = (float*)(ws + 17170432);           // 128 KB
    int*            idx  = (int*)(ws + 17301504);             // 3.15 MB
    float*          Abuf = (float*)(ws + 20447232);           // 4 MB
    float*          Bbuf = (float*)(ws + 24641536);           // 4 MB

    k_encoder<<<256, 128, 0, stream>>>(x, enc_w1, enc_b1, enc_w2, enc_b2,
                                       hA, d2A, hbfA, tilA, d2bA);

    float* hin = hA;   float* d2in = d2A;   float* d2bin = d2bA;
    unsigned short* hbfin = hbfA; unsigned short* tilin = tilA;
    float* hout = hB;  float* d2out = d2B;  float* d2bout = d2bB;
    unsigned short* hbfout = hbfB; unsigned short* tilout = tilB;

    for (int l = 0; l < 3; ++l) {
        // pool ids (u16) alias the NEXT til buffer: dead until k_aggregate
        // writes it (stream-ordered after k_refine consumed the pool).
        unsigned short* mgs = tilout;
        k_scan<<<512, 512, 0, stream>>>(tilin, hbfin, d2bin, mgs);
        k_refine<<<2048, 128, 0, stream>>>(mgs, hin, d2in,
                                           conv_w[l], conv_b[l], idx, Abuf, Bbuf);
        if (l < 2) {
            k_aggregate<false><<<256, 128, 0, stream>>>(
                Abuf, Bbuf, idx, hout, d2out, hbfout, tilout, d2bout,
                nullptr, nullptr, nullptr, nullptr, nullptr, nullptr, nullptr);
        } else {
            k_aggregate<true><<<256, 128, 0, stream>>>(
                Abuf, Bbuf, idx, nullptr, nullptr, nullptr, nullptr, nullptr,
                out_w1, out_b1, out_w2, out_b2, out_w3, out_b3, (float*)d_out);
        }
        float* tf; unsigned short* ts;
        tf = hin; hin = hout; hout = tf;
        tf = d2in; d2in = d2out; d2out = tf;
        tf = d2bin; d2bin = d2bout; d2bout = tf;
        ts = hbfin; hbfin = hbfout; hbfout = ts;
        ts = tilin; tilin = tilout; tilout = ts;
    }
}

// Round 14
// 504.481 us; speedup vs baseline: 1.0029x; 1.0029x over previous
//
#include <hip/hip_runtime.h>
#include <cstddef>
#include <cstdint>

#define BN    32768   // B*N
#define NG    4096    // nodes per graph
#define KNN   24
#define KPW   14      // per-lane partial top over its 1/8 candidate subset
#define KM    32      // merged candidate pool for exact refine
#define CHK   128     // candidates per chunk
#define NBQ   64      // queries per knn block
#define STKD  32      // pending-stack depth per lane (8KB/wave)
#define TRIG  28      // flush trigger: pcnt<=27 pre-tile, +4 writes at slots<=31

typedef float f32x4_t __attribute__((ext_vector_type(4)));
typedef short s16x8_t __attribute__((ext_vector_type(8)));

__device__ __forceinline__ float elu_f(float x) {
    return x > 0.f ? x : expm1f(x);
}

__device__ __forceinline__ unsigned short f2bf(float f) {
    unsigned u = __float_as_uint(f);
    unsigned r = (u + 0x7FFFu + ((u >> 16) & 1u)) >> 16;   // RNE
    return (unsigned short)r;
}

__device__ __forceinline__ void gload_lds16(const void* g, void* l) {
    __builtin_amdgcn_global_load_lds(
        (const __attribute__((address_space(1))) unsigned*)g,
        (__attribute__((address_space(3))) unsigned*)l, 16, 0, 0);
}

// pack one node's 32 features: bf16 linear, bf16 MFMA-A-tiled, bf16-consistent d2
__device__ __forceinline__ void pack_node(int n, const float* hv,
    unsigned short* __restrict__ hbf, unsigned short* __restrict__ til,
    float* __restrict__ d2b)
{
    __align__(16) unsigned short us[32];
    float s = 0.f;
#pragma unroll
    for (int k = 0; k < 32; ++k) {
        us[k] = f2bf(hv[k]);
        float v = __uint_as_float(((unsigned)us[k]) << 16);
        s = fmaf(v, v, s);
    }
    d2b[n] = s;
    const uint4* up = reinterpret_cast<const uint4*>(us);
    uint4* lp = reinterpret_cast<uint4*>(hbf + (size_t)n * 32);
#pragma unroll
    for (int j = 0; j < 4; ++j) lp[j] = up[j];
    const int g = n >> 12, ln = n & 4095, tile = ln >> 4, c = ln & 15;
    unsigned short* tb = til + (size_t)g * 131072 + tile * 512 + c * 8;
#pragma unroll
    for (int kg = 0; kg < 4; ++kg)
        *reinterpret_cast<uint4*>(tb + kg * 128) = up[kg];
}

// ---------------- encoder: x[BN,4] -> h[BN,32] (+bf16 pack, d2, d2b) ----------------
// 256 blocks x 128 threads: one block per CU (all 256 CUs active)
__global__ __launch_bounds__(128) void k_encoder(
    const float* __restrict__ x,
    const float* __restrict__ w1, const float* __restrict__ b1,
    const float* __restrict__ w2, const float* __restrict__ b2,
    float* __restrict__ hOut, float* __restrict__ d2Out,
    unsigned short* __restrict__ hbf, unsigned short* __restrict__ til,
    float* __restrict__ d2b)
{
    __shared__ float sw1[4 * 32];
    __shared__ float sb1[32];
    __shared__ float sw2[32 * 32];
    __shared__ float sb2[32];
    int tid = threadIdx.x;
    sw1[tid] = w1[tid];                     // 128 threads, 128 entries
    if (tid < 32) sb1[tid] = b1[tid];
    for (int i = tid; i < 1024; i += 128) sw2[i] = w2[i];
    if (tid >= 32 && tid < 64) sb2[tid - 32] = b2[tid - 32];
    __syncthreads();

    int node = blockIdx.x * 128 + tid;
    float4 xv = reinterpret_cast<const float4*>(x)[node];

    float h1[32];
#pragma unroll
    for (int o = 0; o < 32; ++o) {
        float s = sb1[o];
        s = fmaf(xv.x, sw1[o], s);
        s = fmaf(xv.y, sw1[32 + o], s);
        s = fmaf(xv.z, sw1[64 + o], s);
        s = fmaf(xv.w, sw1[96 + o], s);
        h1[o] = elu_f(s);
    }
    float h2[32];
    float d2 = 0.f;
#pragma unroll
    for (int o = 0; o < 32; ++o) {
        float s = sb2[o];
#pragma unroll
        for (int f = 0; f < 32; ++f) s = fmaf(h1[f], sw2[f * 32 + o], s);
        float v = elu_f(s);
        h2[o] = v;
        d2 = fmaf(v, v, d2);
    }
    float4* hp = reinterpret_cast<float4*>(hOut) + (size_t)node * 8;
#pragma unroll
    for (int j = 0; j < 8; ++j)
        hp[j] = make_float4(h2[4 * j], h2[4 * j + 1], h2[4 * j + 2], h2[4 * j + 3]);
    d2Out[node] = d2;
    pack_node(node, h2, hbf, til, d2b);
}

// sorted-ascending chain insert into top[KPW]
#define CHAIN14(nk_) do { \
    unsigned nk = (nk_); \
    _Pragma("unroll") \
    for (int jj = 0; jj < KPW; ++jj) { \
        unsigned tj = top[jj]; \
        unsigned lo = nk < tj ? nk : tj; \
        unsigned hi = nk < tj ? tj : nk; \
        top[jj] = lo; nk = hi; \
    } \
} while (0)

// ------------- MFMA kNN scan + parallel rank-to-pool -------------
// 512 blocks x 512 threads; block = 64 queries, 8 waves = 4 query tiles x 2
// cand-tile parities; 2 blocks/CU (grid-capped, 16 waves/CU). The scan is
// VALU-issue-bound (73% VALUBusy); the dominant dynamic cost is flush
// iterations where wave-max pcnt drives the loop and below-max lanes chain
// no-op keys (wave64 exec can't skip them). STKD 16->32 (8KB/wave stacks,
// TRIG 28) cuts flush count ~3x -> ~30% fewer flush iterations. d2 staged in
// LDS (16KB; R13's L2-direct read cost ~1.5%). LDS total 80KB -> 2 blocks/CU
// (the grid cap anyway). Accept path branchless/exec-free; per-lane sorted
// top-14; rank-to-pool v2 (q-major stride-15 lists, identity mapping).
__global__ __launch_bounds__(512, 4) void k_scan(
    const unsigned short* __restrict__ til,
    const unsigned short* __restrict__ hbf,
    const float* __restrict__ d2b,
    unsigned short* __restrict__ mgs)
{
    __shared__ __align__(16) unsigned char smem[81920];
    constexpr int SD2 = 0;        // 16KB whole-graph bf16-consistent d2
    constexpr int STK = 16384;    // 8 waves x 8192B pending stacks (32 deep)
    constexpr int LST = 16384;    // lists reuse stacks after drain: 30720B

    const int tid = threadIdx.x;
    const int lane = tid & 63;
    const int wid = __builtin_amdgcn_readfirstlane(tid >> 6);
    const int qt = wid >> 1;
    const int par = wid & 1;
    const int bid = blockIdx.x;
    const int g = bid >> 6;
    const int gbase = g << 12;
    const int blockq = (bid & 63) * NBQ;
    const int qnode = gbase + blockq + qt * 16 + (lane & 15);
    const int rg = (lane >> 4) * 4;   // candidate row group base within tile

    // stage whole-graph d2 (4096 floats) once: 2 passes x 8 waves x 1KB
    gload_lds16(d2b + gbase + wid * 256 + lane * 4, smem + SD2 + wid * 1024);
    gload_lds16(d2b + gbase + 2048 + wid * 256 + lane * 4,
                smem + SD2 + 8192 + wid * 1024);

    // B fragment: query (lane&15) of this wave's tile, k-slice (lane>>4)*8..+8
    s16x8_t bfrag = *reinterpret_cast<const s16x8_t*>(
        hbf + (size_t)qnode * 32 + (lane >> 4) * 8);
    const float qd2 = d2b[qnode];
    const float nqd2h = -0.5f * qd2;

    unsigned top[KPW];
#pragma unroll
    for (int j = 0; j < KPW; ++j) top[j] = 0xFFFFFFFFu;
    unsigned thresh = 0xFFFFFFFFu;
    int pcnt = 0;

    // this wave's A-fragment stream base: tiles {par, par+2, par+4, par+6}
    const char* gtw = (const char*)til + (size_t)g * 262144
                    + (size_t)par * 1024 + (size_t)lane * 16;
    const float* d2s = reinterpret_cast<const float*>(smem + SD2);
    // per-lane element pointer into this wave's stack: slot j at stkl[j*64]
    unsigned* stkl = reinterpret_cast<unsigned*>(smem + STK + wid * 8192) + lane;

    __syncthreads();   // d2 staged

    // prologue: prefetch chunk 0 A-fragments into registers
    s16x8_t af[4];
#pragma unroll
    for (int i = 0; i < 4; ++i)
        af[i] = *reinterpret_cast<const s16x8_t*>(gtw + i * 2048);

    for (int c = 0; c < 32; ++c) {
        s16x8_t an[4];
        if (c < 31) {
#pragma unroll
            for (int i = 0; i < 4; ++i)
                an[i] = *reinterpret_cast<const s16x8_t*>(
                    gtw + (size_t)(c + 1) * 8192 + i * 2048);
        } else {
#pragma unroll
            for (int i = 0; i < 4; ++i) an[i] = af[i];
        }
        // candidate d2 for this chunk's 4 tiles (LDS, broadcast within 16 lanes)
        f32x4_t cv[4];
#pragma unroll
        for (int i = 0; i < 4; ++i)
            cv[i] = *reinterpret_cast<const f32x4_t*>(
                d2s + c * 128 + (i * 2 + par) * 16 + rg);
#pragma unroll
        for (int i = 0; i < 4; ++i) {
            const int t = i * 2 + par;
            f32x4_t acc;
#pragma unroll
            for (int r = 0; r < 4; ++r) acc[r] = fmaf(-0.5f, cv[i][r], nqd2h);
            acc = __builtin_amdgcn_mfma_f32_16x16x32_bf16(af[i], bfrag, acc, 0, 0, 0);
            const int cid0 = c * CHK + t * 16 + rg;
#pragma unroll
            for (int r = 0; r < 4; ++r) {
                // acc = -(d/2) <= 0; unsigned-ascending bit pattern == ascending d.
                unsigned key = (__float_as_uint(acc[r]) & 0xFFFFF000u)
                             | (unsigned)(cid0 + r);
                // branchless, exec-free accept
                stkl[pcnt * 64] = key;
                pcnt += (key < thresh) ? 1 : 0;
            }
            if (__any(pcnt >= TRIG)) {
#pragma unroll 1
                for (int j = 0; j < STKD; ++j) {
                    if (!__any(pcnt > j)) break;
                    unsigned kk = stkl[j * 64];                   // uncond read
                    unsigned k = (j < pcnt) ? kk : 0xFFFFFFFFu;   // select
                    CHAIN14(k);
                }
                pcnt = 0;
                thresh = top[KPW - 1];
            }
        }
#pragma unroll
        for (int i = 0; i < 4; ++i) af[i] = an[i];
    }
    // final drain
#pragma unroll 1
    for (int j = 0; j < STKD; ++j) {
        if (!__any(pcnt > j)) break;
        unsigned kk = stkl[j * 64];
        unsigned k = (j < pcnt) ? kk : 0xFFFFFFFFu;
        CHAIN14(k);
    }
    __syncthreads();   // all drains done before list region overwrites stacks

    // dump sorted lists: q-major, stride-15 (list (q,li) at lst + q*120 + li*15)
    unsigned* lst = reinterpret_cast<unsigned*>(smem + LST);
    const int q_d  = qt * 16 + (lane & 15);   // this thread's query
    const int li_d = par * 4 + (lane >> 4);   // this thread's list id
    {
        unsigned* myrow = lst + q_d * 120 + li_d * 15;
#pragma unroll
        for (int j = 0; j < KPW; ++j) myrow[j] = top[j];
    }
    __syncthreads();

    // parallel rank-to-pool (identity mapping: my list is top[] in regs).
    // rank(top[j]) = j + sum over 7 peers of #{peer key < top[j]}.
    {
        int rk[KPW];
#pragma unroll
        for (int j = 0; j < KPW; ++j) rk[j] = j;
        const unsigned* base = lst + q_d * 120;
#pragma unroll 1
        for (int u = 1; u < 8; ++u) {
            const unsigned* pl = base + ((li_d + u) & 7) * 15;
            unsigned pk[KPW];
#pragma unroll
            for (int k = 0; k < KPW; ++k) pk[k] = pl[k];   // independent reads
#pragma unroll
            for (int k = 0; k < KPW; ++k) {
#pragma unroll
                for (int j = 0; j < KPW; ++j)
                    rk[j] += (pk[k] < top[j]) ? 1 : 0;
            }
        }
        unsigned short* mrow = mgs + (size_t)(gbase + blockq + q_d) * 32;
#pragma unroll
        for (int j = 0; j < KPW; ++j)
            if (rk[j] < KM) mrow[rk[j]] = (unsigned short)(top[j] & 0xFFFu);
    }
}

// ------------- refine: exact top-24 from the KM pool + A/Bv precompute -------------
// 2048 blocks x 128 threads, 16 queries/block (8 lanes/query), one barrier.
// P2 is COOPERATIVE: per candidate, the query's 8 lanes load the row
// coalesced (8 x 16B = one 128B segment) and butterfly-reduce partial dots
// (__shfl_xor width=8) so every lane holds all 32 exact distances in
// statically-indexed registers. Rank-select is lane-local. A/B reads the
// full q row from a 2KB LDS stage (broadcast reads, conflict-free).
__global__ __launch_bounds__(128) void k_refine(
    const unsigned short* __restrict__ mgs,
    const float* __restrict__ hf,
    const float* __restrict__ d2x,
    const float* __restrict__ cw, const float* __restrict__ cb,
    int* __restrict__ idxOut,
    float* __restrict__ Abuf, float* __restrict__ Bbuf)
{
    __shared__ float sw[2048];
    __shared__ float sb[32];
    __shared__ __align__(16) float shq[16][32];   // block's 16 q rows

    const int tid = threadIdx.x;
    const int bid = blockIdx.x;
    const int g = bid >> 8;
    const int gbase = g << 12;
    const int blockq = (bid & 255) * 16;

    const int q  = tid >> 3;        // 0..15
    const int s0 = tid & 7;
    const int qn = gbase + blockq + q;

    // my 16B chunk of the q row (feeds P2 partial dots AND the LDS stage)
    const float4 qc = reinterpret_cast<const float4*>(hf)[(size_t)qn * 8 + s0];

    for (int i = tid; i < 2048; i += 128) sw[i] = cw[i];
    if (tid < 32) sb[tid] = cb[tid];
    *reinterpret_cast<float4*>(&shq[q][s0 * 4]) = qc;
    __syncthreads();   // the only barrier

    const float qd2e = d2x[qn];

    // P2: cooperative exact distances; all 32 land in per-lane registers
    float dall[32];
    float d_own[4];
    int cid_own[4];
#pragma unroll
    for (int i = 0; i < 4; ++i) { d_own[i] = 0.f; cid_own[i] = 0; }
#pragma unroll
    for (int s = 0; s < 32; ++s) {
        const int cid = (int)mgs[(size_t)qn * 32 + s];   // group-uniform load
        const int cn = gbase + cid;
        const float4 cc = reinterpret_cast<const float4*>(hf)[(size_t)cn * 8 + s0];
        float p = qc.x * cc.x;
        p = fmaf(qc.y, cc.y, p);
        p = fmaf(qc.z, cc.z, p);
        p = fmaf(qc.w, cc.w, p);
        p += __shfl_xor(p, 1, 8);
        p += __shfl_xor(p, 2, 8);
        p += __shfl_xor(p, 4, 8);   // all 8 lanes: full dot
        const float dv = fmaf(-2.f, p, qd2e + d2x[cn]);
        dall[s] = dv;
        // capture owned slots (s & 7 == s0) with static destination index
        const bool own = ((s & 7) == s0);
        d_own[s >> 3]   = own ? dv  : d_own[s >> 3];
        cid_own[s >> 3] = own ? cid : cid_own[s >> 3];
    }

    // P3: lane-local rank-select of owned cands (slots s0+8i); ranks unique
    {
        int* o = idxOut + (size_t)qn * KNN;
#pragma unroll
        for (int i = 0; i < 4; ++i) {
            const int mys = s0 + 8 * i;
            const float di = d_own[i];
            int rank = 0;
#pragma unroll
            for (int j = 0; j < 32; ++j)
                rank += (dall[j] < di || (dall[j] == di && j < mys)) ? 1 : 0;
            if (rank < KNN) o[rank] = cid_own[i];
        }
    }

    // A/B precompute: A = h@(W1-W2)+b, Bv = h@W2 (full q row from LDS stage)
    {
        const int o0 = s0 * 4;
        const float* hr = shq[q];
        float4 s1 = make_float4(0.f, 0.f, 0.f, 0.f);
        float4 s2 = make_float4(0.f, 0.f, 0.f, 0.f);
#pragma unroll
        for (int f = 0; f < 32; ++f) {
            float hv = hr[f];
            float4 wa = *reinterpret_cast<const float4*>(sw + f * 32 + o0);
            float4 wb = *reinterpret_cast<const float4*>(sw + (32 + f) * 32 + o0);
            s1.x = fmaf(hv, wa.x, s1.x); s1.y = fmaf(hv, wa.y, s1.y);
            s1.z = fmaf(hv, wa.z, s1.z); s1.w = fmaf(hv, wa.w, s1.w);
            s2.x = fmaf(hv, wb.x, s2.x); s2.y = fmaf(hv, wb.y, s2.y);
            s2.z = fmaf(hv, wb.z, s2.z); s2.w = fmaf(hv, wb.w, s2.w);
        }
        float4 bv = *reinterpret_cast<const float4*>(sb + o0);
        float4 av = make_float4(s1.x - s2.x + bv.x, s1.y - s2.y + bv.y,
                                s1.z - s2.z + bv.z, s1.w - s2.w + bv.w);
        *reinterpret_cast<float4*>(Abuf + (size_t)qn * 32 + o0) = av;
        *reinterpret_cast<float4*>(Bbuf + (size_t)qn * 32 + o0) = s2;
    }
}

// ------------- aggregate: h_out = elu(A + max_k Bv[nbr]); LAST: fused output MLP -------------
template <bool LAST>
__global__ __launch_bounds__(128) void k_aggregate(
    const float* __restrict__ A, const float* __restrict__ Bv,
    const int* __restrict__ idx,
    float* __restrict__ hOut, float* __restrict__ d2Out,
    unsigned short* __restrict__ hbf, unsigned short* __restrict__ til,
    float* __restrict__ d2b,
    const float* __restrict__ w1, const float* __restrict__ b1,
    const float* __restrict__ w2, const float* __restrict__ b2,
    const float* __restrict__ w3, const float* __restrict__ b3,
    float* __restrict__ out)
{
    __shared__ float sw1[1024];
    __shared__ float sb1[32];
    __shared__ float sw2[512];
    __shared__ float sb2[16];
    __shared__ float sw3[128];
    __shared__ float sb3[8];
    int tid = threadIdx.x;
    if (LAST) {
        for (int i = tid; i < 1024; i += 128) sw1[i] = w1[i];
        for (int i = tid; i < 512; i += 128) sw2[i] = w2[i];
        sw3[tid] = w3[tid];                      // 128 threads, 128 entries
        if (tid < 32) sb1[tid] = b1[tid];
        if (tid >= 32 && tid < 48) sb2[tid - 32] = b2[tid - 32];
        if (tid >= 48 && tid < 56) sb3[tid - 48] = b3[tid - 48];
        __syncthreads();
    }

    int node = blockIdx.x * 128 + tid;
    int g = node >> 12;
    const int* ip = idx + (size_t)node * KNN;

    float4 m[8];
#pragma unroll
    for (int j = 0; j < 8; ++j) m[j] = make_float4(-1e30f, -1e30f, -1e30f, -1e30f);

    for (int k = 0; k < KNN; ++k) {
        int cand = (g << 12) + ip[k];
        const float4* bp = reinterpret_cast<const float4*>(Bv) + (size_t)cand * 8;
#pragma unroll
        for (int j = 0; j < 8; ++j) {
            float4 b = bp[j];
            m[j].x = fmaxf(m[j].x, b.x);
            m[j].y = fmaxf(m[j].y, b.y);
            m[j].z = fmaxf(m[j].z, b.z);
            m[j].w = fmaxf(m[j].w, b.w);
        }
    }
    const float4* ap = reinterpret_cast<const float4*>(A) + (size_t)node * 8;
    float hv[32];
    float d2 = 0.f;
#pragma unroll
    for (int j = 0; j < 8; ++j) {
        float4 a = ap[j];
        float4 v;
        v.x = elu_f(a.x + m[j].x);
        v.y = elu_f(a.y + m[j].y);
        v.z = elu_f(a.z + m[j].z);
        v.w = elu_f(a.w + m[j].w);
        d2 = fmaf(v.x, v.x, d2);
        d2 = fmaf(v.y, v.y, d2);
        d2 = fmaf(v.z, v.z, d2);
        d2 = fmaf(v.w, v.w, d2);
        hv[4 * j] = v.x; hv[4 * j + 1] = v.y; hv[4 * j + 2] = v.z; hv[4 * j + 3] = v.w;
    }

    if (!LAST) {
        float4* hp = reinterpret_cast<float4*>(hOut) + (size_t)node * 8;
#pragma unroll
        for (int j = 0; j < 8; ++j)
            hp[j] = make_float4(hv[4 * j], hv[4 * j + 1], hv[4 * j + 2], hv[4 * j + 3]);
        d2Out[node] = d2;
        pack_node(node, hv, hbf, til, d2b);
    } else {
        float o1[32];
#pragma unroll
        for (int o = 0; o < 32; ++o) {
            float s = sb1[o];
#pragma unroll
            for (int f = 0; f < 32; ++f) s = fmaf(hv[f], sw1[f * 32 + o], s);
            o1[o] = elu_f(s);
        }
        float o2[16];
#pragma unroll
        for (int o = 0; o < 16; ++o) {
            float s = sb2[o];
#pragma unroll
            for (int f = 0; f < 32; ++f) s = fmaf(o1[f], sw2[f * 16 + o], s);
            o2[o] = elu_f(s);
        }
        float o3[8];
#pragma unroll
        for (int o = 0; o < 8; ++o) {
            float s = sb3[o];
#pragma unroll
            for (int f = 0; f < 16; ++f) s = fmaf(o2[f], sw3[f * 8 + o], s);
            o3[o] = s;
        }
        float4* op = reinterpret_cast<float4*>(out) + (size_t)node * 2;
        op[0] = make_float4(o3[0], o3[1], o3[2], o3[3]);
        op[1] = make_float4(o3[4], o3[5], o3[6], o3[7]);
        out[(size_t)BN * 8 + node] = (float)(node >> 12);
    }
}

extern "C" void kernel_launch(void* const* d_in, const int* in_sizes, int n_in,
                              void* d_out, int out_size, void* d_ws, size_t ws_size,
                              hipStream_t stream)
{
    (void)in_sizes; (void)n_in; (void)out_size; (void)ws_size;
    const float* x      = (const float*)d_in[0];
    const float* enc_w1 = (const float*)d_in[2];
    const float* enc_b1 = (const float*)d_in[3];
    const float* enc_w2 = (const float*)d_in[4];
    const float* enc_b2 = (const float*)d_in[5];
    const float* conv_w[3] = { (const float*)d_in[6], (const float*)d_in[8], (const float*)d_in[10] };
    const float* conv_b[3] = { (const float*)d_in[7], (const float*)d_in[9], (const float*)d_in[11] };
    const float* out_w1 = (const float*)d_in[12];
    const float* out_b1 = (const float*)d_in[13];
    const float* out_w2 = (const float*)d_in[14];
    const float* out_b2 = (const float*)d_in[15];
    const float* out_w3 = (const float*)d_in[16];
    const float* out_b3 = (const float*)d_in[17];

    char* ws = (char*)d_ws;
    float*          hA   = (float*)(ws + 0);                  // 4 MB
    float*          hB   = (float*)(ws + 4194304);            // 4 MB
    unsigned short* hbfA = (unsigned short*)(ws + 8388608);   // 2 MB
    unsigned short* hbfB = (unsigned short*)(ws + 10485760);  // 2 MB
    unsigned short* tilA = (unsigned short*)(ws + 12582912);  // 2 MB
    unsigned short* tilB = (unsigned short*)(ws + 14680064);  // 2 MB
    float*          d2A  = (float*)(ws + 16777216);           // 128 KB
    float*          d2B  = (float*)(ws + 16908288);           // 128 KB
    float*          d2bA = (float*)(ws + 17039360);           // 128 KB
    float*          d2bB = (float*)(ws + 17170432);           // 128 KB
    int*            idx  = (int*)(ws + 17301504);             // 3.15 MB
    float*          Abuf = (float*)(ws + 20447232);           // 4 MB
    float*          Bbuf = (float*)(ws + 24641536);           // 4 MB

    k_encoder<<<256, 128, 0, stream>>>(x, enc_w1, enc_b1, enc_w2, enc_b2,
                                       hA, d2A, hbfA, tilA, d2bA);

    float* hin = hA;   float* d2in = d2A;   float* d2bin = d2bA;
    unsigned short* hbfin = hbfA; unsigned short* tilin = tilA;
    float* hout = hB;  float* d2out = d2B;  float* d2bout = d2bB;
    unsigned short* hbfout = hbfB; unsigned short* tilout = tilB;

    for (int l = 0; l < 3; ++l) {
        // pool ids (u16) alias the NEXT til buffer: dead until k_aggregate
        // writes it (stream-ordered after k_refine consumed the pool).
        unsigned short* mgs = tilout;
        k_scan<<<512, 512, 0, stream>>>(tilin, hbfin, d2bin, mgs);
        k_refine<<<2048, 128, 0, stream>>>(mgs, hin, d2in,
                                           conv_w[l], conv_b[l], idx, Abuf, Bbuf);
        if (l < 2) {
            k_aggregate<false><<<256, 128, 0, stream>>>(
                Abuf, Bbuf, idx, hout, d2out, hbfout, tilout, d2bout,
                nullptr, nullptr, nullptr, nullptr, nullptr, nullptr, nullptr);
        } else {
            k_aggregate<true><<<256, 128, 0, stream>>>(
                Abuf, Bbuf, idx, nullptr, nullptr, nullptr, nullptr, nullptr,
                out_w1, out_b1, out_w2, out_b2, out_w3, out_b3, (float*)d_out);
        }
        float* tf; unsigned short* ts;
        tf = hin; hin = hout; hout = tf;
        tf = d2in; d2in = d2out; d2out = tf;
        tf = d2bin; d2bin = d2bout; d2bout = tf;
        ts = hbfin; hbfin = hbfout; hbfout = ts;
        ts = tilin; tilin = tilout; tilout = ts;
    }
}

// Round 15
// 502.161 us; speedup vs baseline: 1.0076x; 1.0046x over previous
//
#include <hip/hip_runtime.h>
#include <cstddef>
#include <cstdint>

#define BN    32768   // B*N
#define NG    4096    // nodes per graph
#define KNN   24
#define KPW   14      // per-lane partial top over its 1/8 candidate subset
#define KM    32      // merged candidate pool for exact refine
#define CHK   128     // candidates per chunk
#define NBQ   64      // queries per knn block
#define STKD  16      // pending-stack depth per lane
#define TRIG  13      // flush trigger: pcnt<=12 pre-tile, +4 writes at slots<=15

typedef float f32x4_t __attribute__((ext_vector_type(4)));
typedef short s16x8_t __attribute__((ext_vector_type(8)));

__device__ __forceinline__ float elu_f(float x) {
    return x > 0.f ? x : expm1f(x);
}

__device__ __forceinline__ unsigned short f2bf(float f) {
    unsigned u = __float_as_uint(f);
    unsigned r = (u + 0x7FFFu + ((u >> 16) & 1u)) >> 16;   // RNE
    return (unsigned short)r;
}

__device__ __forceinline__ void gload_lds16(const void* g, void* l) {
    __builtin_amdgcn_global_load_lds(
        (const __attribute__((address_space(1))) unsigned*)g,
        (__attribute__((address_space(3))) unsigned*)l, 16, 0, 0);
}

// pack one node's 32 features: bf16 linear, bf16 MFMA-A-tiled, bf16-consistent d2
__device__ __forceinline__ void pack_node(int n, const float* hv,
    unsigned short* __restrict__ hbf, unsigned short* __restrict__ til,
    float* __restrict__ d2b)
{
    __align__(16) unsigned short us[32];
    float s = 0.f;
#pragma unroll
    for (int k = 0; k < 32; ++k) {
        us[k] = f2bf(hv[k]);
        float v = __uint_as_float(((unsigned)us[k]) << 16);
        s = fmaf(v, v, s);
    }
    d2b[n] = s;
    const uint4* up = reinterpret_cast<const uint4*>(us);
    uint4* lp = reinterpret_cast<uint4*>(hbf + (size_t)n * 32);
#pragma unroll
    for (int j = 0; j < 4; ++j) lp[j] = up[j];
    const int g = n >> 12, ln = n & 4095, tile = ln >> 4, c = ln & 15;
    unsigned short* tb = til + (size_t)g * 131072 + tile * 512 + c * 8;
#pragma unroll
    for (int kg = 0; kg < 4; ++kg)
        *reinterpret_cast<uint4*>(tb + kg * 128) = up[kg];
}

// ---------------- encoder: x[BN,4] -> h[BN,32] (+bf16 pack, d2, d2b) ----------------
// 256 blocks x 128 threads: one block per CU (all 256 CUs active)
__global__ __launch_bounds__(128) void k_encoder(
    const float* __restrict__ x,
    const float* __restrict__ w1, const float* __restrict__ b1,
    const float* __restrict__ w2, const float* __restrict__ b2,
    float* __restrict__ hOut, float* __restrict__ d2Out,
    unsigned short* __restrict__ hbf, unsigned short* __restrict__ til,
    float* __restrict__ d2b)
{
    __shared__ float sw1[4 * 32];
    __shared__ float sb1[32];
    __shared__ float sw2[32 * 32];
    __shared__ float sb2[32];
    int tid = threadIdx.x;
    sw1[tid] = w1[tid];                     // 128 threads, 128 entries
    if (tid < 32) sb1[tid] = b1[tid];
    for (int i = tid; i < 1024; i += 128) sw2[i] = w2[i];
    if (tid >= 32 && tid < 64) sb2[tid - 32] = b2[tid - 32];
    __syncthreads();

    int node = blockIdx.x * 128 + tid;
    float4 xv = reinterpret_cast<const float4*>(x)[node];

    float h1[32];
#pragma unroll
    for (int o = 0; o < 32; ++o) {
        float s = sb1[o];
        s = fmaf(xv.x, sw1[o], s);
        s = fmaf(xv.y, sw1[32 + o], s);
        s = fmaf(xv.z, sw1[64 + o], s);
        s = fmaf(xv.w, sw1[96 + o], s);
        h1[o] = elu_f(s);
    }
    float h2[32];
    float d2 = 0.f;
#pragma unroll
    for (int o = 0; o < 32; ++o) {
        float s = sb2[o];
#pragma unroll
        for (int f = 0; f < 32; ++f) s = fmaf(h1[f], sw2[f * 32 + o], s);
        float v = elu_f(s);
        h2[o] = v;
        d2 = fmaf(v, v, d2);
    }
    float4* hp = reinterpret_cast<float4*>(hOut) + (size_t)node * 8;
#pragma unroll
    for (int j = 0; j < 8; ++j)
        hp[j] = make_float4(h2[4 * j], h2[4 * j + 1], h2[4 * j + 2], h2[4 * j + 3]);
    d2Out[node] = d2;
    pack_node(node, h2, hbf, til, d2b);
}

// sorted-ascending chain insert into top[KPW]
#define CHAIN14(nk_) do { \
    unsigned nk = (nk_); \
    _Pragma("unroll") \
    for (int jj = 0; jj < KPW; ++jj) { \
        unsigned tj = top[jj]; \
        unsigned lo = nk < tj ? nk : tj; \
        unsigned hi = nk < tj ? tj : nk; \
        top[jj] = lo; nk = hi; \
    } \
} while (0)

// ------------- MFMA kNN scan + parallel rank-to-pool -------------
// 512 blocks x 512 threads; block = 64 queries, 8 waves = 4 query tiles x 2
// cand-tile parities. Scan is barrier-free; A-fragments stream global(L2)->
// register; whole-graph d2 (16KB) staged to LDS once. Selection keys are raw
// MFMA acc bits; accept path branchless/exec-free; per-lane sorted top-14 via
// 16-deep stacks. Pool formation (rank-to-pool v2): q-major stride-15 list
// layout; identity mapping (my list = top[] regs, only 7x14 peer keys read,
// unconditional unrolled ds_reads); 196 branchless cmp-adds/peer. Keys unique
// -> ranks unique -> pool set identical to the exact serial merge.
// [session-final: best-measured config — R12, total 502.1us, scan 113.6us.
//  Probed and null/regressed: barrier-free vs staged (R1), deep stacks
//  (R2/R14), branchless accept (R4), 2x TLP (R3/R5/R6/R13), drain pipelining
//  (R7). Scan is VALU-issue-bound at 73% / 16 waves/CU; measured standalone
//  floor ~100us incl. rank — remaining headroom ~8% of total.]
__global__ __launch_bounds__(512, 4) void k_scan(
    const unsigned short* __restrict__ til,
    const unsigned short* __restrict__ hbf,
    const float* __restrict__ d2b,
    unsigned short* __restrict__ mgs)
{
    __shared__ __align__(16) unsigned char smem[49152];
    constexpr int SD2 = 0;        // 16KB whole-graph bf16-consistent d2
    constexpr int STK = 16384;    // 8 waves x 4096B pending stacks (16 deep)
    constexpr int LST = 16384;    // lists (reuse stacks after drain): 7680 w

    const int tid = threadIdx.x;
    const int lane = tid & 63;
    const int wid = __builtin_amdgcn_readfirstlane(tid >> 6);
    const int qt = wid >> 1;
    const int par = wid & 1;
    const int bid = blockIdx.x;
    const int g = bid >> 6;
    const int gbase = g << 12;
    const int blockq = (bid & 63) * NBQ;
    const int qnode = gbase + blockq + qt * 16 + (lane & 15);
    const int rg = (lane >> 4) * 4;   // candidate row group base within tile

    // stage whole-graph d2 (4096 floats) once: 2 passes x 8 waves x 1KB
    gload_lds16(d2b + gbase + wid * 256 + lane * 4, smem + SD2 + wid * 1024);
    gload_lds16(d2b + gbase + 2048 + wid * 256 + lane * 4,
                smem + SD2 + 8192 + wid * 1024);

    // B fragment: query (lane&15) of this wave's tile, k-slice (lane>>4)*8..+8
    s16x8_t bfrag = *reinterpret_cast<const s16x8_t*>(
        hbf + (size_t)qnode * 32 + (lane >> 4) * 8);
    const float qd2 = d2b[qnode];
    const float nqd2h = -0.5f * qd2;

    unsigned top[KPW];
#pragma unroll
    for (int j = 0; j < KPW; ++j) top[j] = 0xFFFFFFFFu;
    unsigned thresh = 0xFFFFFFFFu;
    int pcnt = 0;

    // this wave's A-fragment stream base: tiles {par, par+2, par+4, par+6}
    const char* gtw = (const char*)til + (size_t)g * 262144
                    + (size_t)par * 1024 + (size_t)lane * 16;
    const float* d2s = reinterpret_cast<const float*>(smem + SD2);
    // per-lane element pointer into this wave's stack: slot j at stkl[j*64]
    unsigned* stkl = reinterpret_cast<unsigned*>(smem + STK + wid * 4096) + lane;

    __syncthreads();   // d2 staged

    // prologue: prefetch chunk 0 A-fragments into registers
    s16x8_t af[4];
#pragma unroll
    for (int i = 0; i < 4; ++i)
        af[i] = *reinterpret_cast<const s16x8_t*>(gtw + i * 2048);

    for (int c = 0; c < 32; ++c) {
        s16x8_t an[4];
        if (c < 31) {
#pragma unroll
            for (int i = 0; i < 4; ++i)
                an[i] = *reinterpret_cast<const s16x8_t*>(
                    gtw + (size_t)(c + 1) * 8192 + i * 2048);
        } else {
#pragma unroll
            for (int i = 0; i < 4; ++i) an[i] = af[i];
        }
        // candidate d2 for this chunk's 4 tiles (LDS, broadcast within 16 lanes)
        f32x4_t cv[4];
#pragma unroll
        for (int i = 0; i < 4; ++i)
            cv[i] = *reinterpret_cast<const f32x4_t*>(
                d2s + c * 128 + (i * 2 + par) * 16 + rg);
#pragma unroll
        for (int i = 0; i < 4; ++i) {
            const int t = i * 2 + par;
            f32x4_t acc;
#pragma unroll
            for (int r = 0; r < 4; ++r) acc[r] = fmaf(-0.5f, cv[i][r], nqd2h);
            acc = __builtin_amdgcn_mfma_f32_16x16x32_bf16(af[i], bfrag, acc, 0, 0, 0);
            const int cid0 = c * CHK + t * 16 + rg;
#pragma unroll
            for (int r = 0; r < 4; ++r) {
                // acc = -(d/2) <= 0; unsigned-ascending bit pattern == ascending d.
                unsigned key = (__float_as_uint(acc[r]) & 0xFFFFF000u)
                             | (unsigned)(cid0 + r);
                // branchless, exec-free accept
                stkl[pcnt * 64] = key;
                pcnt += (key < thresh) ? 1 : 0;
            }
            if (__any(pcnt >= TRIG)) {
#pragma unroll 1
                for (int j = 0; j < STKD; ++j) {
                    if (!__any(pcnt > j)) break;
                    unsigned kk = stkl[j * 64];                   // uncond read
                    unsigned k = (j < pcnt) ? kk : 0xFFFFFFFFu;   // select
                    CHAIN14(k);
                }
                pcnt = 0;
                thresh = top[KPW - 1];
            }
        }
#pragma unroll
        for (int i = 0; i < 4; ++i) af[i] = an[i];
    }
    // final drain
#pragma unroll 1
    for (int j = 0; j < STKD; ++j) {
        if (!__any(pcnt > j)) break;
        unsigned kk = stkl[j * 64];
        unsigned k = (j < pcnt) ? kk : 0xFFFFFFFFu;
        CHAIN14(k);
    }
    __syncthreads();   // all drains done before list region overwrites stacks

    // dump sorted lists: q-major, stride-15 (list (q,li) at lst + q*120 + li*15)
    unsigned* lst = reinterpret_cast<unsigned*>(smem + LST);
    const int q_d  = qt * 16 + (lane & 15);   // this thread's query
    const int li_d = par * 4 + (lane >> 4);   // this thread's list id
    {
        unsigned* myrow = lst + q_d * 120 + li_d * 15;
#pragma unroll
        for (int j = 0; j < KPW; ++j) myrow[j] = top[j];
    }
    __syncthreads();

    // parallel rank-to-pool (identity mapping: my list is top[] in regs).
    // rank(top[j]) = j + sum over 7 peers of #{peer key < top[j]}.
    {
        int rk[KPW];
#pragma unroll
        for (int j = 0; j < KPW; ++j) rk[j] = j;
        const unsigned* base = lst + q_d * 120;
#pragma unroll 1
        for (int u = 1; u < 8; ++u) {
            const unsigned* pl = base + ((li_d + u) & 7) * 15;
            unsigned pk[KPW];
#pragma unroll
            for (int k = 0; k < KPW; ++k) pk[k] = pl[k];   // independent reads
#pragma unroll
            for (int k = 0; k < KPW; ++k) {
#pragma unroll
                for (int j = 0; j < KPW; ++j)
                    rk[j] += (pk[k] < top[j]) ? 1 : 0;
            }
        }
        unsigned short* mrow = mgs + (size_t)(gbase + blockq + q_d) * 32;
#pragma unroll
        for (int j = 0; j < KPW; ++j)
            if (rk[j] < KM) mrow[rk[j]] = (unsigned short)(top[j] & 0xFFFu);
    }
}

// ------------- refine: exact top-24 from the KM pool + A/Bv precompute -------------
// 2048 blocks x 128 threads, 16 queries/block (8 lanes/query), one barrier.
// P2 is COOPERATIVE: per candidate, the query's 8 lanes load the row
// coalesced (8 x 16B = one 128B segment) and butterfly-reduce partial dots
// (__shfl_xor width=8) so every lane holds all 32 exact distances in
// statically-indexed registers. Rank-select is lane-local. A/B reads the
// full q row from a 2KB LDS stage (broadcast reads, conflict-free).
__global__ __launch_bounds__(128) void k_refine(
    const unsigned short* __restrict__ mgs,
    const float* __restrict__ hf,
    const float* __restrict__ d2x,
    const float* __restrict__ cw, const float* __restrict__ cb,
    int* __restrict__ idxOut,
    float* __restrict__ Abuf, float* __restrict__ Bbuf)
{
    __shared__ float sw[2048];
    __shared__ float sb[32];
    __shared__ __align__(16) float shq[16][32];   // block's 16 q rows

    const int tid = threadIdx.x;
    const int bid = blockIdx.x;
    const int g = bid >> 8;
    const int gbase = g << 12;
    const int blockq = (bid & 255) * 16;

    const int q  = tid >> 3;        // 0..15
    const int s0 = tid & 7;
    const int qn = gbase + blockq + q;

    // my 16B chunk of the q row (feeds P2 partial dots AND the LDS stage)
    const float4 qc = reinterpret_cast<const float4*>(hf)[(size_t)qn * 8 + s0];

    for (int i = tid; i < 2048; i += 128) sw[i] = cw[i];
    if (tid < 32) sb[tid] = cb[tid];
    *reinterpret_cast<float4*>(&shq[q][s0 * 4]) = qc;
    __syncthreads();   // the only barrier

    const float qd2e = d2x[qn];

    // P2: cooperative exact distances; all 32 land in per-lane registers
    float dall[32];
    float d_own[4];
    int cid_own[4];
#pragma unroll
    for (int i = 0; i < 4; ++i) { d_own[i] = 0.f; cid_own[i] = 0; }
#pragma unroll
    for (int s = 0; s < 32; ++s) {
        const int cid = (int)mgs[(size_t)qn * 32 + s];   // group-uniform load
        const int cn = gbase + cid;
        const float4 cc = reinterpret_cast<const float4*>(hf)[(size_t)cn * 8 + s0];
        float p = qc.x * cc.x;
        p = fmaf(qc.y, cc.y, p);
        p = fmaf(qc.z, cc.z, p);
        p = fmaf(qc.w, cc.w, p);
        p += __shfl_xor(p, 1, 8);
        p += __shfl_xor(p, 2, 8);
        p += __shfl_xor(p, 4, 8);   // all 8 lanes: full dot
        const float dv = fmaf(-2.f, p, qd2e + d2x[cn]);
        dall[s] = dv;
        // capture owned slots (s & 7 == s0) with static destination index
        const bool own = ((s & 7) == s0);
        d_own[s >> 3]   = own ? dv  : d_own[s >> 3];
        cid_own[s >> 3] = own ? cid : cid_own[s >> 3];
    }

    // P3: lane-local rank-select of owned cands (slots s0+8i); ranks unique
    {
        int* o = idxOut + (size_t)qn * KNN;
#pragma unroll
        for (int i = 0; i < 4; ++i) {
            const int mys = s0 + 8 * i;
            const float di = d_own[i];
            int rank = 0;
#pragma unroll
            for (int j = 0; j < 32; ++j)
                rank += (dall[j] < di || (dall[j] == di && j < mys)) ? 1 : 0;
            if (rank < KNN) o[rank] = cid_own[i];
        }
    }

    // A/B precompute: A = h@(W1-W2)+b, Bv = h@W2 (full q row from LDS stage)
    {
        const int o0 = s0 * 4;
        const float* hr = shq[q];
        float4 s1 = make_float4(0.f, 0.f, 0.f, 0.f);
        float4 s2 = make_float4(0.f, 0.f, 0.f, 0.f);
#pragma unroll
        for (int f = 0; f < 32; ++f) {
            float hv = hr[f];
            float4 wa = *reinterpret_cast<const float4*>(sw + f * 32 + o0);
            float4 wb = *reinterpret_cast<const float4*>(sw + (32 + f) * 32 + o0);
            s1.x = fmaf(hv, wa.x, s1.x); s1.y = fmaf(hv, wa.y, s1.y);
            s1.z = fmaf(hv, wa.z, s1.z); s1.w = fmaf(hv, wa.w, s1.w);
            s2.x = fmaf(hv, wb.x, s2.x); s2.y = fmaf(hv, wb.y, s2.y);
            s2.z = fmaf(hv, wb.z, s2.z); s2.w = fmaf(hv, wb.w, s2.w);
        }
        float4 bv = *reinterpret_cast<const float4*>(sb + o0);
        float4 av = make_float4(s1.x - s2.x + bv.x, s1.y - s2.y + bv.y,
                                s1.z - s2.z + bv.z, s1.w - s2.w + bv.w);
        *reinterpret_cast<float4*>(Abuf + (size_t)qn * 32 + o0) = av;
        *reinterpret_cast<float4*>(Bbuf + (size_t)qn * 32 + o0) = s2;
    }
}

// ------------- aggregate: h_out = elu(A + max_k Bv[nbr]); LAST: fused output MLP -------------
template <bool LAST>
__global__ __launch_bounds__(128) void k_aggregate(
    const float* __restrict__ A, const float* __restrict__ Bv,
    const int* __restrict__ idx,
    float* __restrict__ hOut, float* __restrict__ d2Out,
    unsigned short* __restrict__ hbf, unsigned short* __restrict__ til,
    float* __restrict__ d2b,
    const float* __restrict__ w1, const float* __restrict__ b1,
    const float* __restrict__ w2, const float* __restrict__ b2,
    const float* __restrict__ w3, const float* __restrict__ b3,
    float* __restrict__ out)
{
    __shared__ float sw1[1024];
    __shared__ float sb1[32];
    __shared__ float sw2[512];
    __shared__ float sb2[16];
    __shared__ float sw3[128];
    __shared__ float sb3[8];
    int tid = threadIdx.x;
    if (LAST) {
        for (int i = tid; i < 1024; i += 128) sw1[i] = w1[i];
        for (int i = tid; i < 512; i += 128) sw2[i] = w2[i];
        sw3[tid] = w3[tid];                      // 128 threads, 128 entries
        if (tid < 32) sb1[tid] = b1[tid];
        if (tid >= 32 && tid < 48) sb2[tid - 32] = b2[tid - 32];
        if (tid >= 48 && tid < 56) sb3[tid - 48] = b3[tid - 48];
        __syncthreads();
    }

    int node = blockIdx.x * 128 + tid;
    int g = node >> 12;
    const int* ip = idx + (size_t)node * KNN;

    float4 m[8];
#pragma unroll
    for (int j = 0; j < 8; ++j) m[j] = make_float4(-1e30f, -1e30f, -1e30f, -1e30f);

    for (int k = 0; k < KNN; ++k) {
        int cand = (g << 12) + ip[k];
        const float4* bp = reinterpret_cast<const float4*>(Bv) + (size_t)cand * 8;
#pragma unroll
        for (int j = 0; j < 8; ++j) {
            float4 b = bp[j];
            m[j].x = fmaxf(m[j].x, b.x);
            m[j].y = fmaxf(m[j].y, b.y);
            m[j].z = fmaxf(m[j].z, b.z);
            m[j].w = fmaxf(m[j].w, b.w);
        }
    }
    const float4* ap = reinterpret_cast<const float4*>(A) + (size_t)node * 8;
    float hv[32];
    float d2 = 0.f;
#pragma unroll
    for (int j = 0; j < 8; ++j) {
        float4 a = ap[j];
        float4 v;
        v.x = elu_f(a.x + m[j].x);
        v.y = elu_f(a.y + m[j].y);
        v.z = elu_f(a.z + m[j].z);
        v.w = elu_f(a.w + m[j].w);
        d2 = fmaf(v.x, v.x, d2);
        d2 = fmaf(v.y, v.y, d2);
        d2 = fmaf(v.z, v.z, d2);
        d2 = fmaf(v.w, v.w, d2);
        hv[4 * j] = v.x; hv[4 * j + 1] = v.y; hv[4 * j + 2] = v.z; hv[4 * j + 3] = v.w;
    }

    if (!LAST) {
        float4* hp = reinterpret_cast<float4*>(hOut) + (size_t)node * 8;
#pragma unroll
        for (int j = 0; j < 8; ++j)
            hp[j] = make_float4(hv[4 * j], hv[4 * j + 1], hv[4 * j + 2], hv[4 * j + 3]);
        d2Out[node] = d2;
        pack_node(node, hv, hbf, til, d2b);
    } else {
        float o1[32];
#pragma unroll
        for (int o = 0; o < 32; ++o) {
            float s = sb1[o];
#pragma unroll
            for (int f = 0; f < 32; ++f) s = fmaf(hv[f], sw1[f * 32 + o], s);
            o1[o] = elu_f(s);
        }
        float o2[16];
#pragma unroll
        for (int o = 0; o < 16; ++o) {
            float s = sb2[o];
#pragma unroll
            for (int f = 0; f < 32; ++f) s = fmaf(o1[f], sw2[f * 16 + o], s);
            o2[o] = elu_f(s);
        }
        float o3[8];
#pragma unroll
        for (int o = 0; o < 8; ++o) {
            float s = sb3[o];
#pragma unroll
            for (int f = 0; f < 16; ++f) s = fmaf(o2[f], sw3[f * 8 + o], s);
            o3[o] = s;
        }
        float4* op = reinterpret_cast<float4*>(out) + (size_t)node * 2;
        op[0] = make_float4(o3[0], o3[1], o3[2], o3[3]);
        op[1] = make_float4(o3[4], o3[5], o3[6], o3[7]);
        out[(size_t)BN * 8 + node] = (float)(node >> 12);
    }
}

extern "C" void kernel_launch(void* const* d_in, const int* in_sizes, int n_in,
                              void* d_out, int out_size, void* d_ws, size_t ws_size,
                              hipStream_t stream)
{
    (void)in_sizes; (void)n_in; (void)out_size; (void)ws_size;
    const float* x      = (const float*)d_in[0];
    const float* enc_w1 = (const float*)d_in[2];
    const float* enc_b1 = (const float*)d_in[3];
    const float* enc_w2 = (const float*)d_in[4];
    const float* enc_b2 = (const float*)d_in[5];
    const float* conv_w[3] = { (const float*)d_in[6], (const float*)d_in[8], (const float*)d_in[10] };
    const float* conv_b[3] = { (const float*)d_in[7], (const float*)d_in[9], (const float*)d_in[11] };
    const float* out_w1 = (const float*)d_in[12];
    const float* out_b1 = (const float*)d_in[13];
    const float* out_w2 = (const float*)d_in[14];
    const float* out_b2 = (const float*)d_in[15];
    const float* out_w3 = (const float*)d_in[16];
    const float* out_b3 = (const float*)d_in[17];

    char* ws = (char*)d_ws;
    float*          hA   = (float*)(ws + 0);                  // 4 MB
    float*          hB   = (float*)(ws + 4194304);            // 4 MB
    unsigned short* hbfA = (unsigned short*)(ws + 8388608);   // 2 MB
    unsigned short* hbfB = (unsigned short*)(ws + 10485760);  // 2 MB
    unsigned short* tilA = (unsigned short*)(ws + 12582912);  // 2 MB
    unsigned short* tilB = (unsigned short*)(ws + 14680064);  // 2 MB
    float*          d2A  = (float*)(ws + 16777216);           // 128 KB
    float*          d2B  = (float*)(ws + 16908288);           // 128 KB
    float*          d2bA = (float*)(ws + 17039360);           // 128 KB
    float*          d2bB = (float*)(ws + 17170432);           // 128 KB
    int*            idx  = (int*)(ws + 17301504);             // 3.15 MB
    float*          Abuf = (float*)(ws + 20447232);           // 4 MB
    float*          Bbuf = (float*)(ws + 24641536);           // 4 MB

    k_encoder<<<256, 128, 0, stream>>>(x, enc_w1, enc_b1, enc_w2, enc_b2,
                                       hA, d2A, hbfA, tilA, d2bA);

    float* hin = hA;   float* d2in = d2A;   float* d2bin = d2bA;
    unsigned short* hbfin = hbfA; unsigned short* tilin = tilA;
    float* hout = hB;  float* d2out = d2B;  float* d2bout = d2bB;
    unsigned short* hbfout = hbfB; unsigned short* tilout = tilB;

    for (int l = 0; l < 3; ++l) {
        // pool ids (u16) alias the NEXT til buffer: dead until k_aggregate
        // writes it (stream-ordered after k_refine consumed the pool).
        unsigned short* mgs = tilout;
        k_scan<<<512, 512, 0, stream>>>(tilin, hbfin, d2bin, mgs);
        k_refine<<<2048, 128, 0, stream>>>(mgs, hin, d2in,
                                           conv_w[l], conv_b[l], idx, Abuf, Bbuf);
        if (l < 2) {
            k_aggregate<false><<<256, 128, 0, stream>>>(
                Abuf, Bbuf, idx, hout, d2out, hbfout, tilout, d2bout,
                nullptr, nullptr, nullptr, nullptr, nullptr, nullptr, nullptr);
        } else {
            k_aggregate<true><<<256, 128, 0, stream>>>(
                Abuf, Bbuf, idx, nullptr, nullptr, nullptr, nullptr, nullptr,
                out_w1, out_b1, out_w2, out_b2, out_w3, out_b3, (float*)d_out);
        }
        float* tf; unsigned short* ts;
        tf = hin; hin = hout; hout = tf;
        tf = d2in; d2in = d2out; d2out = tf;
        tf = d2bin; d2bin = d2bout; d2bout = tf;
        ts = hbfin; hbfin = hbfout; hbfout = ts;
        ts = tilin; tilin = tilout; tilout = ts;
    }
}